// Round 2
// baseline (199.317 us; speedup 1.0000x reference)
//
#include <hip/hip_runtime.h>

typedef _Float16 half2v __attribute__((ext_vector_type(2)));
typedef _Float16 half4 __attribute__((ext_vector_type(4)));
typedef _Float16 half8 __attribute__((ext_vector_type(8)));
typedef float floatx4 __attribute__((ext_vector_type(4)));

#define B_   8
#define SE   4096
#define SD   4096
#define D_   128
#define NT   64      // K/V rows per tile
#define LDB  136
#define LOG2E 1.44269504f

// async 16B global->LDS: per-lane global address, wave-uniform LDS base (+lane*16 by HW)
__device__ __forceinline__ void cp16_async(const _Float16* g, _Float16* l) {
    __builtin_amdgcn_global_load_lds((const __attribute__((address_space(1))) unsigned int*)g,
                                     (__attribute__((address_space(3))) unsigned int*)l, 16, 0, 0);
}

__device__ __forceinline__ float dot2acc(half2v a, half2v b, float c) {
#if __has_builtin(__builtin_amdgcn_fdot2)
    return __builtin_amdgcn_fdot2(a, b, c, false);
#else
    return c + (float)a[0] * (float)b[0] + (float)a[1] * (float)b[1];
#endif
}

// ---------- prep 0: Wt16 = fp16(W^T), Wtlo = fp16(W^T - Wt16)  (error split) ----------
// Transposed so the flash prologue's q' = h @ W matmul reads B-fragments row-major.
__global__ __launch_bounds__(256) void wprep(const float* __restrict__ W,
                                             _Float16* __restrict__ Wt16,
                                             _Float16* __restrict__ Wtlo) {
    int i = blockIdx.x * 256 + threadIdx.x;   // grid 64 -> 16384
    int d = i >> 7, e = i & 127;
    float w = W[i];                            // W[d][e]
    _Float16 hi = (_Float16)w;
    Wt16[e * 128 + d] = hi;
    Wtlo[e * 128 + d] = (_Float16)(w - (float)hi);
}

// ---------- prep 1: kc = fp16(b) row-major, vT = fp16(b^T)  (pure streaming) ----------
__global__ __launch_bounds__(256) void bprep(const float* __restrict__ b,
                                             _Float16* __restrict__ kc,
                                             _Float16* __restrict__ vT) {
    __shared__ _Float16 bs[64 * LDB];   // 17408 B
    const int bb = blockIdx.y, s0 = blockIdx.x * 64;
    const int tid = threadIdx.x;

    const float* bg = b + ((size_t)bb * SE + s0) * D_;
    _Float16* kg = kc + ((size_t)bb * SE + s0) * D_;
    #pragma unroll
    for (int it = 0; it < 4; ++it) {
        int idx = tid + it * 256;
        int row = idx >> 4, seg = idx & 15;
        const float* src = bg + row * D_ + seg * 8;
        float4 a = *(const float4*)src;
        float4 c = *(const float4*)(src + 4);
        half8 hv;
        hv[0] = (_Float16)a.x; hv[1] = (_Float16)a.y; hv[2] = (_Float16)a.z; hv[3] = (_Float16)a.w;
        hv[4] = (_Float16)c.x; hv[5] = (_Float16)c.y; hv[6] = (_Float16)c.z; hv[7] = (_Float16)c.w;
        *(half8*)(kg + row * D_ + seg * 8) = hv;       // coalesced fp16 K image
        *(half8*)(bs + row * LDB + seg * 8) = hv;      // stage for transpose
    }
    __syncthreads();

    // transpose: each thread does an 8s x 4d micro-tile -> 16B s-contiguous stores
    const int sg = tid & 7, dg = tid >> 3;             // s = sg*8..+7, d = dg*4..+3
    half4 rowv[8];
    #pragma unroll
    for (int j = 0; j < 8; ++j)
        rowv[j] = *(const half4*)(bs + (sg * 8 + j) * LDB + dg * 4);
    #pragma unroll
    for (int dd = 0; dd < 4; ++dd) {
        half8 o;
        #pragma unroll
        for (int j = 0; j < 8; ++j) o[j] = rowv[j][dd];
        *(half8*)(vT + ((size_t)bb * D_ + dg * 4 + dd) * SE + s0 + sg * 8) = o;
    }
}

// ---------- fused flash attention ----------
// 256 threads = 4 waves = 2 wq (32 q rows each; 2 Q-frags) x 2 ws (32 s each).
// Per wave-tile: 32 MFMA on 16 ds_read_b128 (2x MFMA-per-LDS-read vs round 1;
// per-CU LDS-read cycles halve since each block now covers 64 q rows).
// Prologue computes q' = (h @ W)*log2e in-block with error-split W (kvprep matmul
// eliminated), overlapped with tile-0 DMA. 64 KB LDS, 2 blocks/CU.
__global__ __launch_bounds__(256, 2) void flash(const float* __restrict__ h,
                                                const _Float16* __restrict__ Wt16,
                                                const _Float16* __restrict__ Wtlo,
                                                const _Float16* __restrict__ kc,
                                                const _Float16* __restrict__ vT,
                                                float* __restrict__ out) {
    __shared__ _Float16 KV[2][16384];   // per buf: K image 8192 halves + V image 8192

    const int bb   = blockIdx.y;
    const int q0   = blockIdx.x * 64;
    const int tid  = threadIdx.x;      // 0..255
    const int wave = tid >> 6;         // 0..3
    const int wq   = wave >> 1;        // q-group 0..1 (32 q rows each)
    const int ws   = wave & 1;         // s-group 0..1 (32 s each per tile)
    const int lane = tid & 63;
    const int l15  = lane & 15;
    const int quad = lane >> 4;

    const _Float16* kbase = kc + (size_t)bb * SE * D_;
    const _Float16* vbase = vT + (size_t)bb * D_ * SE;

    // per-lane DMA gather offsets; 1024 chunks per image, 4 rounds of 256 threads.
    // K rows permuted so lane P values are s-contiguous (x32 PV A-frag, round-1 trick).
    int koff[4], voff[4];
    #pragma unroll
    for (int it = 0; it < 4; ++it) {
        int i = it * 256 + wave * 64 + lane;      // linear 16B chunk index in image
        int kr = i >> 4, kpp = i & 15;            // K: 64 rows x 16 chunks
        int km = kr & 15;
        int srow = (kr & 32) + ((km >> 2) << 3) + (((kr >> 4) & 1) << 2) + (km & 3);
        koff[it] = srow * D_ + ((kpp ^ km) * 8);
        int vr = i >> 3, vpp = i & 7;             // V: 128 rows x 8 chunks (linear rows)
        voff[it] = vr * SE + ((vpp ^ (vr & 7)) * 8);
    }

    // hoisted LDS read bases
    const _Float16* kA0[4]; const _Float16* kA1[4];
    const _Float16 *vB0, *vB1;
    #pragma unroll
    for (int ks = 0; ks < 4; ++ks) {
        int o = l15 * 128 + (((ks * 4 + quad) ^ l15) * 8) + ws * 4096;
        kA0[ks] = &KV[0][o]; kA1[ks] = &KV[1][o];
    }
    {
        int o = 8192 + l15 * 64 + (((ws * 4 + quad) ^ (l15 & 7)) * 8);
        vB0 = &KV[0][o]; vB1 = &KV[1][o];
    }

    // issue tile 0 DMA into KV[0] (lands while the prologue matmul runs)
    {
        _Float16* buf0 = &KV[0][0];
        #pragma unroll
        for (int it = 0; it < 4; ++it) {
            cp16_async(kbase + koff[it], buf0 + (it * 256 + wave * 64) * 8);
            cp16_async(vbase + voff[it], buf0 + 8192 + (it * 256 + wave * 64) * 8);
        }
    }

    // ---- prologue: q' = (h @ W) * log2e, fp16, LDS round-trip in KV[1] ----
    _Float16* hs = &KV[1][0];          // 64 x LDB = 8704 halves < 16384
    {
        const float* hg = h + ((size_t)bb * SD + q0) * D_;
        #pragma unroll
        for (int it = 0; it < 4; ++it) {
            int idx = tid + it * 256;
            int row = idx >> 4, seg = idx & 15;
            const float* src = hg + row * D_ + seg * 8;
            float4 a = *(const float4*)src;
            float4 c = *(const float4*)(src + 4);
            half8 hv;
            hv[0] = (_Float16)a.x; hv[1] = (_Float16)a.y; hv[2] = (_Float16)a.z; hv[3] = (_Float16)a.w;
            hv[4] = (_Float16)c.x; hv[5] = (_Float16)c.y; hv[6] = (_Float16)c.z; hv[7] = (_Float16)c.w;
            *(half8*)(hs + row * LDB + seg * 8) = hv;
        }
    }
    __syncthreads();
    half8 qf0[4], qf1[4];
    {
        half8 af[4];
        #pragma unroll
        for (int ks = 0; ks < 4; ++ks)
            af[ks] = *(const half8*)(hs + (wave * 16 + l15) * LDB + ks * 32 + quad * 8);
        floatx4 acc[8];
        #pragma unroll
        for (int nt = 0; nt < 8; ++nt) acc[nt] = (floatx4){0.f, 0.f, 0.f, 0.f};
        #pragma unroll
        for (int ks = 0; ks < 4; ++ks) {
            #pragma unroll
            for (int nt = 0; nt < 8; ++nt) {
                half8 bh = *(const half8*)(Wt16 + (size_t)(nt * 16 + l15) * 128 + ks * 32 + quad * 8);
                half8 bl = *(const half8*)(Wtlo + (size_t)(nt * 16 + l15) * 128 + ks * 32 + quad * 8);
                acc[nt] = __builtin_amdgcn_mfma_f32_16x16x32_f16(af[ks], bh, acc[nt], 0, 0, 0);
                acc[nt] = __builtin_amdgcn_mfma_f32_16x16x32_f16(af[ks], bl, acc[nt], 0, 0, 0);
            }
        }
        __syncthreads();   // all hs reads done before overwrite
        #pragma unroll
        for (int nt = 0; nt < 8; ++nt)
            #pragma unroll
            for (int r = 0; r < 4; ++r)
                hs[(wave * 16 + quad * 4 + r) * LDB + nt * 16 + l15] =
                    (_Float16)(acc[nt][r] * LOG2E);
        __syncthreads();
        #pragma unroll
        for (int ks = 0; ks < 4; ++ks) {
            qf0[ks] = *(const half8*)(hs + (wq * 32 + l15) * LDB + ks * 32 + quad * 8);
            qf1[ks] = *(const half8*)(hs + (wq * 32 + 16 + l15) * LDB + ks * 32 + quad * 8);
        }
        // no sync here: STEP's top barrier orders these reads vs tile-1 DMA into KV[1]
    }

    floatx4 acc_o0[8], acc_o1[8];
    #pragma unroll
    for (int dt = 0; dt < 8; ++dt) {
        acc_o0[dt] = (floatx4){0.f, 0.f, 0.f, 0.f};
        acc_o1[dt] = (floatx4){0.f, 0.f, 0.f, 0.f};
    }
    float nm0 = 0.f, nm1 = 0.f;        // -(running max, base-2), per q-frag
    float lp0 = 0.f, lp1 = 0.f;        // per-lane partial denominators
    const half2v one2 = { (_Float16)1.f, (_Float16)1.f };

#define RESCALE(MV, NM, LP, ACCS, ACCO)                                               \
    { float mr = fmaxf((MV), __shfl_xor((MV), 16, 64));                               \
      mr = fmaxf(mr, __shfl_xor(mr, 32, 64));                                         \
      float delta = fmaxf(mr, 0.f);                                                   \
      float alpha = exp2f(-delta);                                                    \
      LP *= alpha;                                                                    \
      float ab[4];                                                                    \
      _Pragma("unroll")                                                               \
      for (int r = 0; r < 4; ++r) ab[r] = __shfl(alpha, quad * 4 + r, 64);            \
      _Pragma("unroll")                                                               \
      for (int dt = 0; dt < 8; ++dt)                                                  \
        _Pragma("unroll")                                                             \
        for (int r = 0; r < 4; ++r) ACCO[dt][r] *= ab[r];                             \
      _Pragma("unroll")                                                               \
      for (int stl = 0; stl < 2; ++stl)                                               \
        _Pragma("unroll")                                                             \
        for (int r = 0; r < 4; ++r) ACCS[stl][r] -= delta;                            \
      NM -= delta; }

#define SOFTPACK(ACCS, LP, PA)                                                        \
    { float p0 = exp2f(ACCS[0][0]), p1 = exp2f(ACCS[0][1]);                           \
      float p2 = exp2f(ACCS[0][2]), p3 = exp2f(ACCS[0][3]);                           \
      float p4 = exp2f(ACCS[1][0]), p5 = exp2f(ACCS[1][1]);                           \
      float p6 = exp2f(ACCS[1][2]), p7 = exp2f(ACCS[1][3]);                           \
      half2v c0 = __builtin_bit_cast(half2v, __builtin_amdgcn_cvt_pkrtz(p0, p1));     \
      half2v c1 = __builtin_bit_cast(half2v, __builtin_amdgcn_cvt_pkrtz(p2, p3));     \
      half2v c2 = __builtin_bit_cast(half2v, __builtin_amdgcn_cvt_pkrtz(p4, p5));     \
      half2v c3 = __builtin_bit_cast(half2v, __builtin_amdgcn_cvt_pkrtz(p6, p7));     \
      LP = dot2acc(c0, one2, LP);                                                     \
      LP = dot2acc(c1, one2, LP);                                                     \
      LP = dot2acc(c2, one2, LP);                                                     \
      LP = dot2acc(c3, one2, LP);                                                     \
      PA[0] = c0[0]; PA[1] = c0[1]; PA[2] = c1[0]; PA[3] = c1[1];                     \
      PA[4] = c2[0]; PA[5] = c2[1]; PA[6] = c3[0]; PA[7] = c3[1]; }

// one tile step: compute from (KA,VBP), prefetch tile T+1 into NBUF
#define STEP(T, KA, VBP, NBUF)                                                        \
  {                                                                                   \
    __syncthreads();   /* vmcnt drain -> tile T landed for all waves */               \
    if ((T) + 1 < SE / NT) {                                                          \
      const _Float16* kt = kbase + (size_t)((T) + 1) * (NT * D_);                     \
      const _Float16* vt = vbase + (size_t)((T) + 1) * NT;                            \
      _Float16* bufn = (NBUF);                                                        \
      _Pragma("unroll")                                                               \
      for (int it = 0; it < 4; ++it) {                                                \
        cp16_async(kt + koff[it], bufn + (it * 256 + wave * 64) * 8);                 \
        cp16_async(vt + voff[it], bufn + 8192 + (it * 256 + wave * 64) * 8);          \
      }                                                                               \
    }                                                                                 \
    floatx4 accs0[2], accs1[2];                                                       \
    accs0[0] = (floatx4){nm0, nm0, nm0, nm0}; accs0[1] = accs0[0];                    \
    accs1[0] = (floatx4){nm1, nm1, nm1, nm1}; accs1[1] = accs1[0];                    \
    _Pragma("unroll")                                                                 \
    for (int ks = 0; ks < 4; ++ks) {                                                  \
      half8 af0 = *(const half8*)(KA[ks]);                                            \
      half8 af1 = *(const half8*)(KA[ks] + 2048);                                     \
      accs0[0] = __builtin_amdgcn_mfma_f32_16x16x32_f16(af0, qf0[ks], accs0[0], 0, 0, 0); \
      accs0[1] = __builtin_amdgcn_mfma_f32_16x16x32_f16(af1, qf0[ks], accs0[1], 0, 0, 0); \
      accs1[0] = __builtin_amdgcn_mfma_f32_16x16x32_f16(af0, qf1[ks], accs1[0], 0, 0, 0); \
      accs1[1] = __builtin_amdgcn_mfma_f32_16x16x32_f16(af1, qf1[ks], accs1[1], 0, 0, 0); \
    }                                                                                 \
    float mv0 = fmaxf(fmaxf(fmaxf(accs0[0][0], accs0[0][1]), fmaxf(accs0[0][2], accs0[0][3])), \
                      fmaxf(fmaxf(accs0[1][0], accs0[1][1]), fmaxf(accs0[1][2], accs0[1][3]))); \
    float mv1 = fmaxf(fmaxf(fmaxf(accs1[0][0], accs1[0][1]), fmaxf(accs1[0][2], accs1[0][3])), \
                      fmaxf(fmaxf(accs1[1][0], accs1[1][1]), fmaxf(accs1[1][2], accs1[1][3]))); \
    if (__ballot((mv0 > 11.5f) || (mv1 > 11.5f)) != 0ull) {                           \
      RESCALE(mv0, nm0, lp0, accs0, acc_o0);                                          \
      RESCALE(mv1, nm1, lp1, accs1, acc_o1);                                          \
    }                                                                                 \
    half8 pA0, pA1;                                                                   \
    SOFTPACK(accs0, lp0, pA0);                                                        \
    SOFTPACK(accs1, lp1, pA1);                                                        \
    _Pragma("unroll")                                                                 \
    for (int dt = 0; dt < 8; ++dt) {                                                  \
      half8 vf = *(const half8*)((VBP) + dt * 1024);                                  \
      acc_o0[dt] = __builtin_amdgcn_mfma_f32_16x16x32_f16(pA0, vf, acc_o0[dt], 0, 0, 0); \
      acc_o1[dt] = __builtin_amdgcn_mfma_f32_16x16x32_f16(pA1, vf, acc_o1[dt], 0, 0, 0); \
    }                                                                                 \
  }

    for (int t = 0; t < SE / NT; t += 2) {
        STEP(t,     kA0, vB0, &KV[1][0]);
        STEP(t + 1, kA1, vB1, &KV[0][0]);
    }
#undef STEP

    // ---- epilogue: finalize per-wave partials, exact cross-wave (s-split) merge ----
    const float m_q0 = -nm0, m_q1 = -nm1;
    float lo0, lo1;
    {
        float l = lp0;
        l += __shfl_xor(l, 16, 64);
        l += __shfl_xor(l, 32, 64);
        lo0 = l;
        l = lp1;
        l += __shfl_xor(l, 16, 64);
        l += __shfl_xor(l, 32, 64);
        lo1 = l;
    }

    __syncthreads();                   // all PV reads of KV done; safe to overwrite
    float* Ob = (float*)&KV[0][0];     // [wq*2+qq][dt][lane] float4 : 32 KB
    float* ml = (float*)&KV[1][0];     // m,l pairs: [wq*32 + qq*16 + q][2] (128 floats)

    if (ws == 1) {
        #pragma unroll
        for (int dt = 0; dt < 8; ++dt) {
            *(floatx4*)(Ob + (((wq * 2 + 0) * 8 + dt) * 64 + lane) * 4) = acc_o0[dt];
            *(floatx4*)(Ob + (((wq * 2 + 1) * 8 + dt) * 64 + lane) * 4) = acc_o1[dt];
        }
        if (quad == 0) {
            *(float2*)(ml + (wq * 32 + l15) * 2)      = make_float2(m_q0, lo0);
            *(float2*)(ml + (wq * 32 + 16 + l15) * 2) = make_float2(m_q1, lo1);
        }
    }
    __syncthreads();
    if (ws == 0) {
#define MERGE(ACC, MQ, LO, QQ)                                                        \
      { float m0r[4], l0r[4], m1r[4], l1r[4];                                         \
        _Pragma("unroll")                                                             \
        for (int r = 0; r < 4; ++r) {                                                 \
            m0r[r] = __shfl((MQ), quad * 4 + r, 64);                                  \
            l0r[r] = __shfl((LO), quad * 4 + r, 64);                                  \
            float2 p = *(float2*)(ml + (wq * 32 + (QQ) * 16 + quad * 4 + r) * 2);     \
            m1r[r] = p.x; l1r[r] = p.y;                                               \
        }                                                                             \
        float a0[4], a1[4], inv[4];                                                   \
        _Pragma("unroll")                                                             \
        for (int r = 0; r < 4; ++r) {                                                 \
            float mm = fmaxf(m0r[r], m1r[r]);                                         \
            a0[r] = exp2f(m0r[r] - mm);                                               \
            a1[r] = exp2f(m1r[r] - mm);                                               \
            inv[r] = 1.f / (l0r[r] * a0[r] + l1r[r] * a1[r]);                         \
        }                                                                             \
        float* orow = out + ((size_t)bb * SD + q0 + wq * 32 + (QQ) * 16 + quad * 4) * D_; \
        _Pragma("unroll")                                                             \
        for (int dt = 0; dt < 8; ++dt) {                                              \
            floatx4 o1 = *(floatx4*)(Ob + (((wq * 2 + (QQ)) * 8 + dt) * 64 + lane) * 4); \
            _Pragma("unroll")                                                         \
            for (int r = 0; r < 4; ++r)                                               \
                orow[(size_t)r * D_ + dt * 16 + l15] =                                \
                    (ACC[dt][r] * a0[r] + o1[r] * a1[r]) * inv[r];                    \
        } }
        MERGE(acc_o0, m_q0, lo0, 0);
        MERGE(acc_o1, m_q1, lo1, 1);
#undef MERGE
    }
#undef RESCALE
#undef SOFTPACK
}

extern "C" void kernel_launch(void* const* d_in, const int* in_sizes, int n_in,
                              void* d_out, int out_size, void* d_ws, size_t ws_size,
                              hipStream_t stream) {
    const float* b = (const float*)d_in[0];   // [B, SE, D]
    const float* h = (const float*)d_in[1];   // [B, SD, D]
    const float* W = (const float*)d_in[2];   // [D, D]
    float* out = (float*)d_out;               // [B, SD, D] fp32

    _Float16* Wt16 = (_Float16*)d_ws;                      // 32 KB
    _Float16* Wtlo = Wt16 + 128 * 128;                     // 32 KB
    _Float16* kc   = Wtlo + 128 * 128;                     // [B, SE, D] fp16
    _Float16* vT   = kc + (size_t)B_ * SE * D_;            // [B, D, SE] fp16

    wprep<<<64, 256, 0, stream>>>(W, Wt16, Wtlo);
    bprep<<<dim3(SE / 64, B_), 256, 0, stream>>>(b, kc, vT);
    flash<<<dim3(SD / 64, B_), 256, 0, stream>>>(h, Wt16, Wtlo, kc, vT, out);
}

// Round 3
// 185.101 us; speedup vs baseline: 1.0768x; 1.0768x over previous
//
#include <hip/hip_runtime.h>

typedef _Float16 half2v __attribute__((ext_vector_type(2)));
typedef _Float16 half4 __attribute__((ext_vector_type(4)));
typedef _Float16 half8 __attribute__((ext_vector_type(8)));
typedef float floatx4 __attribute__((ext_vector_type(4)));

#define B_   8
#define SE   4096
#define SD   4096
#define D_   128
#define NT   64      // K/V rows per tile
#define LDB  136
#define LOG2E 1.44269504f

// async 16B global->LDS: per-lane global address, wave-uniform LDS base (+lane*16 by HW)
__device__ __forceinline__ void cp16_async(const _Float16* g, _Float16* l) {
    __builtin_amdgcn_global_load_lds((const __attribute__((address_space(1))) unsigned int*)g,
                                     (__attribute__((address_space(3))) unsigned int*)l, 16, 0, 0);
}

__device__ __forceinline__ float dot2acc(half2v a, half2v b, float c) {
#if __has_builtin(__builtin_amdgcn_fdot2)
    return __builtin_amdgcn_fdot2(a, b, c, false);
#else
    return c + (float)a[0] * (float)b[0] + (float)a[1] * (float)b[1];
#endif
}

// ---------- prep: kc = fp16(b), vT = fp16(b^T); W error-split folded in ----------
// Wt16[e][d] = fp16(W[d][e]), Wtlo = fp16 residual (same transform as verified wprep).
__global__ __launch_bounds__(256) void bprep(const float* __restrict__ b,
                                             const float* __restrict__ W,
                                             _Float16* __restrict__ kc,
                                             _Float16* __restrict__ vT,
                                             _Float16* __restrict__ Wt16,
                                             _Float16* __restrict__ Wtlo) {
    __shared__ _Float16 bs[64 * LDB];   // 17408 B
    const int bb = blockIdx.y, s0 = blockIdx.x * 64;
    const int tid = threadIdx.x;

    // W fold-in: the 8 blocks with blockIdx.x==0 each convert 1/8 of W (2048 elems)
    if (blockIdx.x == 0) {
        int base = bb * 2048 + tid * 8;
        #pragma unroll
        for (int j = 0; j < 8; ++j) {
            int i = base + j;
            int d = i >> 7, e = i & 127;
            float w = W[i];                    // W[d][e]
            _Float16 hi = (_Float16)w;
            Wt16[e * 128 + d] = hi;
            Wtlo[e * 128 + d] = (_Float16)(w - (float)hi);
        }
    }

    const float* bg = b + ((size_t)bb * SE + s0) * D_;
    _Float16* kg = kc + ((size_t)bb * SE + s0) * D_;
    #pragma unroll
    for (int it = 0; it < 4; ++it) {
        int idx = tid + it * 256;
        int row = idx >> 4, seg = idx & 15;
        const float* src = bg + row * D_ + seg * 8;
        float4 a = *(const float4*)src;
        float4 c = *(const float4*)(src + 4);
        half8 hv;
        hv[0] = (_Float16)a.x; hv[1] = (_Float16)a.y; hv[2] = (_Float16)a.z; hv[3] = (_Float16)a.w;
        hv[4] = (_Float16)c.x; hv[5] = (_Float16)c.y; hv[6] = (_Float16)c.z; hv[7] = (_Float16)c.w;
        *(half8*)(kg + row * D_ + seg * 8) = hv;       // coalesced fp16 K image
        *(half8*)(bs + row * LDB + seg * 8) = hv;      // stage for transpose
    }
    __syncthreads();

    // transpose: each thread does an 8s x 4d micro-tile -> 16B s-contiguous stores
    const int sg = tid & 7, dg = tid >> 3;             // s = sg*8..+7, d = dg*4..+3
    half4 rowv[8];
    #pragma unroll
    for (int j = 0; j < 8; ++j)
        rowv[j] = *(const half4*)(bs + (sg * 8 + j) * LDB + dg * 4);
    #pragma unroll
    for (int dd = 0; dd < 4; ++dd) {
        half8 o;
        #pragma unroll
        for (int j = 0; j < 8; ++j) o[j] = rowv[j][dd];
        *(half8*)(vT + ((size_t)bb * D_ + dg * 4 + dd) * SE + s0 + sg * 8) = o;
    }
}

// ---------- fused flash attention ----------
// ROUND-1 VERIFIED GEOMETRY: 512 threads = 8 waves = 4 wq (16 q rows) x 2 ws (32 s).
// 64 KB LDS -> 2 blocks/CU = 16 waves/CU = 4 waves/SIMD (round-2's 2/SIMD regressed).
// NEW: prologue computes q' = (h @ W) * log2e in-block with error-split W (verified
// in round 2), overlapped with tile-0 DMA; K image is plain fp16(b).
__global__ __launch_bounds__(512, 4) void flash(const float* __restrict__ h,
                                                const _Float16* __restrict__ Wt16,
                                                const _Float16* __restrict__ Wtlo,
                                                const _Float16* __restrict__ kc,
                                                const _Float16* __restrict__ vT,
                                                float* __restrict__ out) {
    __shared__ _Float16 KV[2][16384];   // per buf: K image 8192 halves + V image 8192

    const int bb   = blockIdx.y;
    const int q0   = blockIdx.x * 64;
    const int tid  = threadIdx.x;      // 0..511
    const int wave = tid >> 6;         // 0..7
    const int wq   = wave >> 1;        // q-group 0..3 (16 q rows each)
    const int ws   = wave & 1;         // s-group 0..1 (32 s each per tile)
    const int lane = tid & 63;
    const int l15  = lane & 15;
    const int quad = lane >> 4;

    const _Float16* kbase = kc + (size_t)bb * SE * D_;
    const _Float16* vbase = vT + (size_t)bb * D_ * SE;

    // per-lane DMA gather offsets; 1024 chunks per image, 2 rounds of 512 threads.
    // K rows permuted so lane P values are s-contiguous (x32 PV A-frag).
    int koff[2], voff[2];
    #pragma unroll
    for (int it = 0; it < 2; ++it) {
        int i = it * 512 + wave * 64 + lane;      // linear 16B chunk index in image
        int kr = i >> 4, kpp = i & 15;            // K: 64 rows x 16 chunks
        int km = kr & 15;
        int srow = (kr & 32) + ((km >> 2) << 3) + (((kr >> 4) & 1) << 2) + (km & 3);
        koff[it] = srow * D_ + ((kpp ^ km) * 8);
        int vr = i >> 3, vpp = i & 7;             // V: 128 rows x 8 chunks (linear rows)
        voff[it] = vr * SE + ((vpp ^ (vr & 7)) * 8);
    }

    // hoisted LDS read bases
    const _Float16* kA0[4]; const _Float16* kA1[4];
    const _Float16 *vB0, *vB1;
    #pragma unroll
    for (int ks = 0; ks < 4; ++ks) {
        int o = l15 * 128 + (((ks * 4 + quad) ^ l15) * 8) + ws * 4096;
        kA0[ks] = &KV[0][o]; kA1[ks] = &KV[1][o];
    }
    {
        int o = 8192 + l15 * 64 + (((ws * 4 + quad) ^ (l15 & 7)) * 8);
        vB0 = &KV[0][o]; vB1 = &KV[1][o];
    }

    // issue tile 0 DMA into KV[0] (lands while the prologue matmul runs)
    {
        _Float16* buf0 = &KV[0][0];
        #pragma unroll
        for (int it = 0; it < 2; ++it) {
            cp16_async(kbase + koff[it], buf0 + (it * 512 + wave * 64) * 8);
            cp16_async(vbase + voff[it], buf0 + 8192 + (it * 512 + wave * 64) * 8);
        }
    }

    // ---- prologue: q' = (h @ W) * log2e, fp16, LDS round-trip in KV[1] ----
    _Float16* hs = &KV[1][0];          // 64 x LDB = 8704 halves < 16384
    {
        const float* hg = h + ((size_t)bb * SD + q0) * D_;
        #pragma unroll
        for (int it = 0; it < 2; ++it) {
            int idx = tid + it * 512;
            int row = idx >> 4, seg = idx & 15;
            const float* src = hg + row * D_ + seg * 8;
            float4 a = *(const float4*)src;
            float4 c = *(const float4*)(src + 4);
            half8 hv;
            hv[0] = (_Float16)a.x; hv[1] = (_Float16)a.y; hv[2] = (_Float16)a.z; hv[3] = (_Float16)a.w;
            hv[4] = (_Float16)c.x; hv[5] = (_Float16)c.y; hv[6] = (_Float16)c.z; hv[7] = (_Float16)c.w;
            *(half8*)(hs + row * LDB + seg * 8) = hv;
        }
    }
    __syncthreads();
    half8 qf[4];
    {
        // 8 waves = 4 row-groups (wq) x 2 col-halves (ws): each wave 16q x 64 cols
        half8 af[4];
        #pragma unroll
        for (int ks = 0; ks < 4; ++ks)
            af[ks] = *(const half8*)(hs + (wq * 16 + l15) * LDB + ks * 32 + quad * 8);
        floatx4 acc[4];
        #pragma unroll
        for (int nt = 0; nt < 4; ++nt) acc[nt] = (floatx4){0.f, 0.f, 0.f, 0.f};
        #pragma unroll
        for (int ks = 0; ks < 4; ++ks) {
            #pragma unroll
            for (int nt = 0; nt < 4; ++nt) {
                size_t wo = (size_t)(ws * 64 + nt * 16 + l15) * 128 + ks * 32 + quad * 8;
                half8 bh = *(const half8*)(Wt16 + wo);
                half8 bl = *(const half8*)(Wtlo + wo);
                acc[nt] = __builtin_amdgcn_mfma_f32_16x16x32_f16(af[ks], bh, acc[nt], 0, 0, 0);
                acc[nt] = __builtin_amdgcn_mfma_f32_16x16x32_f16(af[ks], bl, acc[nt], 0, 0, 0);
            }
        }
        __syncthreads();   // all hs reads done before overwrite
        #pragma unroll
        for (int nt = 0; nt < 4; ++nt)
            #pragma unroll
            for (int r = 0; r < 4; ++r)
                hs[(wq * 16 + quad * 4 + r) * LDB + ws * 64 + nt * 16 + l15] =
                    (_Float16)(acc[nt][r] * LOG2E);
        __syncthreads();
        #pragma unroll
        for (int ks = 0; ks < 4; ++ks)
            qf[ks] = *(const half8*)(hs + (wq * 16 + l15) * LDB + ks * 32 + quad * 8);
        // no sync needed: STEP's top barrier orders these reads vs tile-1 DMA into KV[1]
    }

    floatx4 acc_o[8];
    #pragma unroll
    for (int dt = 0; dt < 8; ++dt) acc_o[dt] = (floatx4){0.f, 0.f, 0.f, 0.f};
    float nm = 0.f;       // -(running max, base-2); anchored at 0, deferred-rescale
    float l_part = 0.f;   // per-lane partial denominator
    const half2v one2 = { (_Float16)1.f, (_Float16)1.f };

// one tile step: compute from (KA,VBP), prefetch tile T+1 into NBUF
#define STEP(T, KA, VBP, NBUF)                                                        \
  {                                                                                   \
    __syncthreads();   /* vmcnt drain -> tile T landed for all waves */               \
    if ((T) + 1 < SE / NT) {                                                          \
      const _Float16* kt = kbase + (size_t)((T) + 1) * (NT * D_);                     \
      const _Float16* vt = vbase + (size_t)((T) + 1) * NT;                            \
      _Float16* bufn = (NBUF);                                                        \
      _Pragma("unroll")                                                               \
      for (int it = 0; it < 2; ++it) {                                                \
        cp16_async(kt + koff[it], bufn + (it * 512 + wave * 64) * 8);                 \
        cp16_async(vt + voff[it], bufn + 8192 + (it * 512 + wave * 64) * 8);          \
      }                                                                               \
    }                                                                                 \
    /* S^T = K Q^T, C pre-biased by -m: accs = S - m after MFMA */                    \
    floatx4 accs[2];                                                                  \
    accs[0] = (floatx4){nm, nm, nm, nm};                                              \
    accs[1] = accs[0];                                                                \
    _Pragma("unroll")                                                                 \
    for (int ks = 0; ks < 4; ++ks) {                                                  \
      half8 af0 = *(const half8*)(KA[ks]);                                            \
      half8 af1 = *(const half8*)(KA[ks] + 2048);                                     \
      accs[0] = __builtin_amdgcn_mfma_f32_16x16x32_f16(af0, qf[ks], accs[0], 0, 0, 0);\
      accs[1] = __builtin_amdgcn_mfma_f32_16x16x32_f16(af1, qf[ks], accs[1], 0, 0, 0);\
    }                                                                                 \
    /* relative max via max3-friendly tree (4 ops) */                                 \
    float x0 = fmaxf(fmaxf(accs[0][0], accs[0][1]), accs[0][2]);                      \
    float x1 = fmaxf(fmaxf(accs[0][3], accs[1][0]), accs[1][1]);                      \
    float x2 = fmaxf(fmaxf(accs[1][2], accs[1][3]), x0);                              \
    float mv = fmaxf(x1, x2);                                                         \
    if (__ballot(mv > 11.5f) != 0ull) {   /* rare wave-uniform slow path */           \
      float mr = fmaxf(mv, __shfl_xor(mv, 16, 64));                                   \
      mr = fmaxf(mr, __shfl_xor(mr, 32, 64));                                         \
      float delta = fmaxf(mr, 0.f);                                                   \
      float alpha = exp2f(-delta);                                                    \
      l_part *= alpha;                                                                \
      float ab[4];                                                                    \
      _Pragma("unroll")                                                               \
      for (int r = 0; r < 4; ++r) ab[r] = __shfl(alpha, quad * 4 + r, 64);            \
      _Pragma("unroll")                                                               \
      for (int dt = 0; dt < 8; ++dt)                                                  \
        _Pragma("unroll")                                                             \
        for (int r = 0; r < 4; ++r) acc_o[dt][r] *= ab[r];                            \
      _Pragma("unroll")                                                               \
      for (int stl = 0; stl < 2; ++stl)                                               \
        _Pragma("unroll")                                                             \
        for (int r = 0; r < 4; ++r) accs[stl][r] -= delta;                            \
      nm -= delta;                                                                    \
    }                                                                                 \
    /* P = 2^(S-m); lane holds s = 8*quad..8*quad+7 -> pA IS the x32 PV A-frag */     \
    float p0 = exp2f(accs[0][0]), p1 = exp2f(accs[0][1]);                             \
    float p2 = exp2f(accs[0][2]), p3 = exp2f(accs[0][3]);                             \
    float p4 = exp2f(accs[1][0]), p5 = exp2f(accs[1][1]);                             \
    float p6 = exp2f(accs[1][2]), p7 = exp2f(accs[1][3]);                             \
    half2v c0 = __builtin_bit_cast(half2v, __builtin_amdgcn_cvt_pkrtz(p0, p1));       \
    half2v c1 = __builtin_bit_cast(half2v, __builtin_amdgcn_cvt_pkrtz(p2, p3));       \
    half2v c2 = __builtin_bit_cast(half2v, __builtin_amdgcn_cvt_pkrtz(p4, p5));       \
    half2v c3 = __builtin_bit_cast(half2v, __builtin_amdgcn_cvt_pkrtz(p6, p7));       \
    l_part = dot2acc(c0, one2, l_part);                                               \
    l_part = dot2acc(c1, one2, l_part);                                               \
    l_part = dot2acc(c2, one2, l_part);                                               \
    l_part = dot2acc(c3, one2, l_part);                                               \
    half8 pA;                                                                         \
    pA[0] = c0[0]; pA[1] = c0[1]; pA[2] = c1[0]; pA[3] = c1[1];                       \
    pA[4] = c2[0]; pA[5] = c2[1]; pA[6] = c3[0]; pA[7] = c3[1];                       \
    /* O += P V : B-frag = V^T[d=dt*16+l15][s=ws*32 + quad*8 + 0..7], one b128 */     \
    _Pragma("unroll")                                                                 \
    for (int dt = 0; dt < 8; ++dt) {                                                  \
      half8 vf = *(const half8*)((VBP) + dt * 1024);                                  \
      acc_o[dt] = __builtin_amdgcn_mfma_f32_16x16x32_f16(pA, vf, acc_o[dt], 0, 0, 0); \
    }                                                                                 \
  }

    for (int t = 0; t < SE / NT; t += 2) {
        STEP(t,     kA0, vB0, &KV[1][0]);
        STEP(t + 1, kA1, vB1, &KV[0][0]);
    }
#undef STEP

    // ---- epilogue: finalize per-wave partials, exact cross-wave (s-split) merge ----
    const float m_q = -nm;
    float l_own;
    {
        float l = l_part;
        l += __shfl_xor(l, 16, 64);
        l += __shfl_xor(l, 32, 64);
        l_own = l;                     // denominator partial for q = l15
    }

    __syncthreads();                   // all PV reads of KV done; safe to overwrite
    float* Ob = (float*)&KV[0][0];     // [wq][dt][lane] float4 : 32 KB (8192 floats)
    float* ml = (float*)&KV[1][0];     // m,l pairs: [wq*16 + q][2]  (128 floats)

    if (ws == 1) {
        #pragma unroll
        for (int dt = 0; dt < 8; ++dt)
            *(floatx4*)(Ob + ((wq * 8 + dt) * 64 + lane) * 4) = acc_o[dt];
        if (quad == 0)
            *(float2*)(ml + (wq * 16 + l15) * 2) = make_float2(m_q, l_own);
    }
    __syncthreads();
    if (ws == 0) {
        float m0r[4], l0r[4], m1r[4], l1r[4];
        #pragma unroll
        for (int r = 0; r < 4; ++r) {
            m0r[r] = __shfl(m_q, quad * 4 + r, 64);
            l0r[r] = __shfl(l_own, quad * 4 + r, 64);
            float2 p = *(float2*)(ml + (wq * 16 + quad * 4 + r) * 2);
            m1r[r] = p.x; l1r[r] = p.y;
        }
        float a0[4], a1[4], inv[4];
        #pragma unroll
        for (int r = 0; r < 4; ++r) {
            float mm = fmaxf(m0r[r], m1r[r]);
            a0[r] = exp2f(m0r[r] - mm);
            a1[r] = exp2f(m1r[r] - mm);
            inv[r] = 1.f / (l0r[r] * a0[r] + l1r[r] * a1[r]);
        }
        float* orow = out + ((size_t)bb * SD + q0 + wq * 16 + quad * 4) * D_;
        #pragma unroll
        for (int dt = 0; dt < 8; ++dt) {
            floatx4 o1 = *(floatx4*)(Ob + ((wq * 8 + dt) * 64 + lane) * 4);
            #pragma unroll
            for (int r = 0; r < 4; ++r)
                orow[(size_t)r * D_ + dt * 16 + l15] =
                    (acc_o[dt][r] * a0[r] + o1[r] * a1[r]) * inv[r];
        }
    }
}

extern "C" void kernel_launch(void* const* d_in, const int* in_sizes, int n_in,
                              void* d_out, int out_size, void* d_ws, size_t ws_size,
                              hipStream_t stream) {
    const float* b = (const float*)d_in[0];   // [B, SE, D]
    const float* h = (const float*)d_in[1];   // [B, SD, D]
    const float* W = (const float*)d_in[2];   // [D, D]
    float* out = (float*)d_out;               // [B, SD, D] fp32

    _Float16* Wt16 = (_Float16*)d_ws;                      // 32 KB
    _Float16* Wtlo = Wt16 + 128 * 128;                     // 32 KB
    _Float16* kc   = Wtlo + 128 * 128;                     // [B, SE, D] fp16
    _Float16* vT   = kc + (size_t)B_ * SE * D_;            // [B, D, SE] fp16

    bprep<<<dim3(SE / 64, B_), 256, 0, stream>>>(b, W, kc, vT, Wt16, Wtlo);
    flash<<<dim3(SD / 64, B_), 512, 0, stream>>>(h, Wt16, Wtlo, kc, vT, out);
}